// Round 10
// baseline (218.758 us; speedup 1.0000x reference)
//
#include <hip/hip_runtime.h>

// inputs (8, 64, 16, 32, 32) fp32, embedding (512, 64) fp32
// N = 131072 positions, D = 64, K = 512
// d_out (fp32): [0, 8388608) quantized_st, [8388608] loss, [8388609, ...) indices
#define SPATIAL   16384
#define DIM       64
#define KCODES    512
#define NPOS      131072
#define QST_ELEMS 8388608
#define LOSS_OFF  8388608
#define IDX_OFF   8388609
#define NBLOCKS   (NPOS / 256)     // 512 blocks, 1 thread = 1 position

// --- non-contractable fp32 ops (match numpy's plain mul/add/sub) ---
__device__ __forceinline__ float mul_rn(float a, float b) {
#pragma clang fp contract(off)
    return a * b;
}
__device__ __forceinline__ float add_rn(float a, float b) {
#pragma clang fp contract(off)
    return a + b;
}
__device__ __forceinline__ float sub_rn(float a, float b) {
#pragma clang fp contract(off)
    return a - b;
}

// numpy pairwise_sum for n=64: 8 accumulators strided by 8, then
// ((r0+r1)+(r2+r3))+((r4+r5)+(r6+r7))
__device__ __forceinline__ float np_sumsq64(const float* v) {
    float r[8];
#pragma unroll
    for (int j = 0; j < 8; ++j) r[j] = mul_rn(v[j], v[j]);
#pragma unroll
    for (int i = 8; i < 64; i += 8) {
#pragma unroll
        for (int j = 0; j < 8; ++j) r[j] = add_rn(r[j], mul_rn(v[i + j], v[i + j]));
    }
    return add_rn(add_rn(add_rn(r[0], r[1]), add_rn(r[2], r[3])),
                  add_rn(add_rn(r[4], r[5]), add_rn(r[6], r[7])));
}

// e2[k] = np.sum(embedding**2, axis=1), bit-exact numpy pairwise order
__global__ void vq_e2_kernel(const float* __restrict__ emb, float* __restrict__ e2) {
    int k = blockIdx.x * 64 + threadIdx.x;
    if (k >= KCODES) return;
    float v[DIM];
#pragma unroll
    for (int d = 0; d < DIM; ++d) v[d] = emb[k * DIM + d];
    e2[k] = np_sumsq64(v);
}

// ---- x held in 16 NAMED float4s ----
#define DECLX float4 x0,x1,x2q,x3,x4,x5,x6,x7,x8,x9,x10,x11,x12,x13,x14,x15;

#define LOADX(v,q) \
    v.x = xin[(size_t)(4*(q)+0)*SPATIAL]; \
    v.y = xin[(size_t)(4*(q)+1)*SPATIAL]; \
    v.z = xin[(size_t)(4*(q)+2)*SPATIAL]; \
    v.w = xin[(size_t)(4*(q)+3)*SPATIAL];

// opaque pin once after load (R7-proven pattern -> VGPR=88, x resident)
#define PINQ(v) asm volatile("" : "+v"(v.x), "+v"(v.y), "+v"(v.z), "+v"(v.w));
#define PIN_ALL \
    PINQ(x0)  PINQ(x1)  PINQ(x2q) PINQ(x3) \
    PINQ(x4)  PINQ(x5)  PINQ(x6)  PINQ(x7) \
    PINQ(x8)  PINQ(x9)  PINQ(x10) PINQ(x11) \
    PINQ(x12) PINQ(x13) PINQ(x14) PINQ(x15)

#define SQA(ve,vo) \
    r0 = add_rn(r0, mul_rn(ve.x, ve.x)); r1 = add_rn(r1, mul_rn(ve.y, ve.y)); \
    r2 = add_rn(r2, mul_rn(ve.z, ve.z)); r3 = add_rn(r3, mul_rn(ve.w, ve.w)); \
    r4 = add_rn(r4, mul_rn(vo.x, vo.x)); r5 = add_rn(r5, mul_rn(vo.y, vo.y)); \
    r6 = add_rn(r6, mul_rn(vo.z, vo.z)); r7 = add_rn(r7, mul_rn(vo.w, vo.w));

#define SUMSQ_X2 \
    float r0 = mul_rn(x0.x, x0.x), r1 = mul_rn(x0.y, x0.y); \
    float r2 = mul_rn(x0.z, x0.z), r3 = mul_rn(x0.w, x0.w); \
    float r4 = mul_rn(x1.x, x1.x), r5 = mul_rn(x1.y, x1.y); \
    float r6 = mul_rn(x1.z, x1.z), r7 = mul_rn(x1.w, x1.w); \
    SQA(x2q, x3) SQA(x4, x5) SQA(x6, x7) SQA(x8, x9) \
    SQA(x10, x11) SQA(x12, x13) SQA(x14, x15) \
    const float x2 = add_rn(add_rn(add_rn(r0, r1), add_rn(r2, r3)), \
                            add_rn(add_rn(r4, r5), add_rn(r6, r7)));

// SINGLE-code serial-ascending-d FMA step: 64 staging e-floats fit the SGPR
// file -> 4 back-to-back s_load_dwordx16 + ONE lgkmcnt wait per iteration
// (R7's ILP-2 needed 128 staged floats -> chunk/wait/chunk serial = 950cyc/iter)
#define DSTEP1(v,q) { \
    acc = __builtin_fmaf(v.x, ek[4*(q)+0], acc); \
    acc = __builtin_fmaf(v.y, ek[4*(q)+1], acc); \
    acc = __builtin_fmaf(v.z, ek[4*(q)+2], acc); \
    acc = __builtin_fmaf(v.w, ek[4*(q)+3], acc); }

#define EPIQ(v,q) { \
    float4 e4 = eq4[q]; \
    float dd; \
    dd = sub_rn(e4.x, v.x); oq[(size_t)(4*(q)+0)*SPATIAL] = add_rn(v.x, dd); lsum += (double)mul_rn(dd, dd); \
    dd = sub_rn(e4.y, v.y); oq[(size_t)(4*(q)+1)*SPATIAL] = add_rn(v.y, dd); lsum += (double)mul_rn(dd, dd); \
    dd = sub_rn(e4.z, v.z); oq[(size_t)(4*(q)+2)*SPATIAL] = add_rn(v.z, dd); lsum += (double)mul_rn(dd, dd); \
    dd = sub_rn(e4.w, v.w); oq[(size_t)(4*(q)+3)*SPATIAL] = add_rn(v.w, dd); lsum += (double)mul_rn(dd, dd); }

// Fused kernel: R7 structure (waves_per_eu(2,2) -> proven no-spill VGPR=88)
// + single-code K-iterations (staging fits SGPRs -> one wait per iter; the
// other wave's 128-cyc FMA block hides this wave's ~120-200cyc SMEM latency).
__global__ __launch_bounds__(256)
__attribute__((amdgpu_waves_per_eu(2, 2)))
void vq_main_kernel(const float* __restrict__ in, const float* __restrict__ emb,
                    const float* __restrict__ e2, float* __restrict__ out,
                    double* __restrict__ losspart) {
    __shared__ double lpart[4];
    const int t = threadIdx.x;
    const int p = blockIdx.x * 256 + t;
    const int b = p >> 14;
    const int s = p & 16383;
    const float* xin = in + (size_t)b * (DIM * SPATIAL) + s;

    DECLX
    LOADX(x0, 0)  LOADX(x1, 1)  LOADX(x2q, 2) LOADX(x3, 3)
    LOADX(x4, 4)  LOADX(x5, 5)  LOADX(x6, 6)  LOADX(x7, 7)
    LOADX(x8, 8)  LOADX(x9, 9)  LOADX(x10,10) LOADX(x11,11)
    LOADX(x12,12) LOADX(x13,13) LOADX(x14,14) LOADX(x15,15)
    PIN_ALL
    SUMSQ_X2

    float best = __builtin_inff();
    int bidx = 0;
#pragma unroll 1
    for (int k = 0; k < KCODES; ++k) {
        const float* ek = emb + (size_t)k * DIM;   // block-uniform -> s_load
        float acc = 0.0f;
        DSTEP1(x0, 0)  DSTEP1(x1, 1)  DSTEP1(x2q, 2) DSTEP1(x3, 3)
        DSTEP1(x4, 4)  DSTEP1(x5, 5)  DSTEP1(x6, 6)  DSTEP1(x7, 7)
        DSTEP1(x8, 8)  DSTEP1(x9, 9)  DSTEP1(x10,10) DSTEP1(x11,11)
        DSTEP1(x12,12) DSTEP1(x13,13) DSTEP1(x14,14) DSTEP1(x15,15)
        float dist = sub_rn(add_rn(x2, e2[k]), mul_rn(2.0f, acc));
        if (dist < best) { best = dist; bidx = k; }
    }

    out[IDX_OFF + p] = (float)bidx;

    // epilogue: qst + loss straight from the register-resident x
    const float4* eq4 = (const float4*)(emb + (size_t)bidx * DIM);
    float* oq = out + (size_t)b * (DIM * SPATIAL) + s;
    double lsum = 0.0;
    EPIQ(x0, 0)  EPIQ(x1, 1)  EPIQ(x2q, 2) EPIQ(x3, 3)
    EPIQ(x4, 4)  EPIQ(x5, 5)  EPIQ(x6, 6)  EPIQ(x7, 7)
    EPIQ(x8, 8)  EPIQ(x9, 9)  EPIQ(x10,10) EPIQ(x11,11)
    EPIQ(x12,12) EPIQ(x13,13) EPIQ(x14,14) EPIQ(x15,15)

    // deterministic loss partial: wave shuffle reduce -> ordered 4-wave sum
#pragma unroll
    for (int off = 32; off > 0; off >>= 1) lsum += __shfl_down(lsum, off, 64);
    const int lane = t & 63, wave = t >> 6;
    if (lane == 0) lpart[wave] = lsum;
    __syncthreads();
    if (t == 0) losspart[blockIdx.x] = ((lpart[0] + lpart[1]) + lpart[2]) + lpart[3];
}

// reduce 512 block partials (deterministic fixed-order tree) -> loss scalar
__global__ void vq_finalize_kernel(const double* __restrict__ part,
                                   float* __restrict__ out) {
    __shared__ double sdata[256];
    int t = threadIdx.x;
    sdata[t] = part[t] + part[t + 256];
    __syncthreads();
    for (int stride = 128; stride > 0; stride >>= 1) {
        if (t < stride) sdata[t] = sdata[t] + sdata[t + stride];
        __syncthreads();
    }
    if (t == 0) {
        double m = sdata[0] / (double)QST_ELEMS;
        float mf = (float)m;
        out[LOSS_OFF] = add_rn(mf, mul_rn(0.25f, mf));
    }
}

extern "C" void kernel_launch(void* const* d_in, const int* in_sizes, int n_in,
                              void* d_out, int out_size, void* d_ws, size_t ws_size,
                              hipStream_t stream) {
    const float* in  = (const float*)d_in[0];
    const float* emb = (const float*)d_in[1];
    float* out = (float*)d_out;
    double* losspart = (double*)d_ws;                              // 512 doubles
    float* e2 = (float*)((char*)d_ws + NBLOCKS * sizeof(double));  // 512 floats

    vq_e2_kernel<<<KCODES / 64, 64, 0, stream>>>(emb, e2);
    vq_main_kernel<<<NBLOCKS, 256, 0, stream>>>(in, emb, e2, out, losspart);
    vq_finalize_kernel<<<1, 256, 0, stream>>>(losspart, out);
}